// Round 1
// baseline (1300.595 us; speedup 1.0000x reference)
//
#include <hip/hip_runtime.h>

typedef unsigned short u16;
typedef __bf16 bf16x8 __attribute__((ext_vector_type(8)));
typedef float f32x4 __attribute__((ext_vector_type(4)));

constexpr int Bq  = 4;
constexpr int Sq  = 2048;
constexpr int Hq  = 1024;
constexpr int NHq = 16;
constexpr int HDq = 64;

// workspace layout (bytes, all 256-aligned)
constexpr size_t OFF_XB = 0;            // x bf16:   8192*1024*2 = 16,777,216
constexpr size_t OFF_WB = 16777216;     // Wq,Wk,Wv,Wg,Wo bf16: 5*1M*2 = 10,485,760
constexpr size_t OFF_Q  = 27262976;     // q fp32: 33,554,432
constexpr size_t OFF_K  = 60817408;
constexpr size_t OFF_V  = 94371840;
constexpr size_t OFF_G  = 127926272;
constexpr size_t OFF_O  = 161480704;
constexpr size_t OFF_AL = 195035136;    // alpha: 524,288
constexpr size_t OFF_BE = 195559424;
constexpr size_t OFF_YB = 196083712;    // y bf16: 16,777,216  (end 212,860,928)

__device__ __forceinline__ u16 f2bf(float f) {
  unsigned u = __float_as_uint(f);
  u += 0x7fffu + ((u >> 16) & 1u);
  return (u16)(u >> 16);
}
__device__ __forceinline__ float sigmoidf_(float x) { return 1.f / (1.f + __expf(-x)); }

__device__ __forceinline__ void async16(const u16* g, u16* l) {
  __builtin_amdgcn_global_load_lds((const __attribute__((address_space(1))) void*)(const void*)g,
                                   (__attribute__((address_space(3))) void*)(void*)l, 16, 0, 0);
}

// ---------------- converts ----------------
__global__ __launch_bounds__(256) void cvt_x_kernel(const float* __restrict__ in, u16* __restrict__ outp) {
  const size_t i = ((size_t)blockIdx.x * 256 + threadIdx.x) * 4;
  float4 f = *(const float4*)(in + i);
  ushort4 u; u.x = f2bf(f.x); u.y = f2bf(f.y); u.z = f2bf(f.z); u.w = f2bf(f.w);
  *(ushort4*)(outp + i) = u;
}

__global__ __launch_bounds__(256) void cvt_w_kernel(const float* __restrict__ w0, const float* __restrict__ w1,
    const float* __restrict__ w2, const float* __restrict__ w3, const float* __restrict__ w4,
    u16* __restrict__ outp) {
  const int z = blockIdx.z;
  const float* src = (z == 0) ? w0 : (z == 1) ? w1 : (z == 2) ? w2 : (z == 3) ? w3 : w4;
  const size_t i = ((size_t)blockIdx.x * 256 + threadIdx.x) * 4;
  float4 f = *(const float4*)(src + i);
  ushort4 u; u.x = f2bf(f.x); u.y = f2bf(f.y); u.z = f2bf(f.z); u.w = f2bf(f.w);
  *(ushort4*)(outp + (size_t)z * (1024 * 1024) + i) = u;
}

// ---------------- bf16 MFMA GEMM: C(8192x1024) = A(8192x1024) @ W(1024x1024)^T ----------------
// m97 structure: 128x128 tile, BK=32, global_load_lds w=16, 4 waves, 4x4 16x16x32 acc per wave.
__global__ __launch_bounds__(256) void gemm_bt(const u16* __restrict__ A, const u16* __restrict__ Wb,
    float* __restrict__ C0, float* __restrict__ C1, float* __restrict__ C2, float* __restrict__ C3) {
  constexpr int GK = 1024, GN = 1024;
  __shared__ __align__(16) u16 As[128 * 32];
  __shared__ __align__(16) u16 Bs[128 * 32];
  const int tid = threadIdx.x;
  const int w = tid >> 6, lane = tid & 63;
  const int m0 = blockIdx.x * 128, n0 = blockIdx.y * 128;
  const u16* W = Wb + (size_t)blockIdx.z * (1024 * 1024);
  float* C = (blockIdx.z == 0) ? C0 : (blockIdx.z == 1) ? C1 : (blockIdx.z == 2) ? C2 : C3;
  const int rrow = lane >> 2;          // 0..15 within 16-row chunk
  const int kc8 = (lane & 3) * 8;      // 8-elem k chunk
  const u16* gA = A + (size_t)(m0 + w * 32 + rrow) * GK + kc8;
  const u16* gB = W + (size_t)(n0 + w * 32 + rrow) * GK + kc8;
  u16* lA = As + (w * 32) * 32;        // wave-uniform LDS base; HW scatters lane*16B
  u16* lB = Bs + (w * 32) * 32;
  const int qd = lane >> 4, l15 = lane & 15;
  const int wm = (w >> 1) * 64, wn = (w & 1) * 64;
  f32x4 acc[4][4] = {};
  for (int kt = 0; kt < GK; kt += 32) {
    async16(gA,           lA);
    async16(gA + 16 * GK, lA + 16 * 32);
    async16(gB,           lB);
    async16(gB + 16 * GK, lB + 16 * 32);
    gA += 32; gB += 32;
    __syncthreads();
    bf16x8 af[4], bfr[4];
    #pragma unroll
    for (int i = 0; i < 4; ++i) {
      af[i]  = *(const bf16x8*)(As + (wm + i * 16 + l15) * 32 + qd * 8);
      bfr[i] = *(const bf16x8*)(Bs + (wn + i * 16 + l15) * 32 + qd * 8);
    }
    #pragma unroll
    for (int i = 0; i < 4; ++i)
      #pragma unroll
      for (int j = 0; j < 4; ++j)
        acc[i][j] = __builtin_amdgcn_mfma_f32_16x16x32_bf16(af[i], bfr[j], acc[i][j], 0, 0, 0);
    __syncthreads();
  }
  // C/D layout: col = lane&15, row = (lane>>4)*4 + reg   [measured m89/m91]
  #pragma unroll
  for (int i = 0; i < 4; ++i) {
    const int row = m0 + wm + i * 16 + qd * 4;
    #pragma unroll
    for (int j = 0; j < 4; ++j) {
      const int col = n0 + wn + j * 16 + l15;
      #pragma unroll
      for (int r = 0; r < 4; ++r)
        C[(size_t)(row + r) * GN + col] = acc[i][j][r];
    }
  }
}

// ---------------- alpha/beta: sigmoid(x @ Wab^T + b), 32 outputs per token ----------------
__global__ __launch_bounds__(256) void ab_kernel(const float* __restrict__ x,
    const float* __restrict__ Wa, const float* __restrict__ ba,
    const float* __restrict__ Wb, const float* __restrict__ bb,
    float* __restrict__ al, float* __restrict__ be) {
  __shared__ __align__(16) float xs[1024];
  const int t = blockIdx.x, tid = threadIdx.x;
  const float4* xp = (const float4*)(x + (size_t)t * 1024);
  ((float4*)xs)[tid] = xp[tid];
  __syncthreads();
  const int o = tid >> 3, p = tid & 7;
  const float* w = (o < 16) ? (Wa + (size_t)o * 1024) : (Wb + (size_t)(o - 16) * 1024);
  float s = 0.f;
  for (int i = p * 128; i < p * 128 + 128; i += 4) {
    float4 xv = *(const float4*)(xs + i);
    float4 wv = *(const float4*)(w + i);
    s += xv.x * wv.x + xv.y * wv.y + xv.z * wv.z + xv.w * wv.w;
  }
  s += __shfl_xor(s, 1); s += __shfl_xor(s, 2); s += __shfl_xor(s, 4);
  if (p == 0) {
    const float bias = (o < 16) ? ba[o] : bb[o - 16];
    const float val = sigmoidf_(s + bias);
    if (o < 16) al[(size_t)t * 16 + o] = val;
    else        be[(size_t)t * 16 + (o - 16)] = val;
  }
}

// ---------------- epilogue: l2norm(q), l2norm(k), silu(v) per (token,head) ----------------
__global__ __launch_bounds__(256) void qkv_ep(float* __restrict__ q, float* __restrict__ k, float* __restrict__ v) {
  const int gh = blockIdx.x * 4 + (threadIdx.x >> 6);
  const int lane = threadIdx.x & 63;
  const size_t idx = (size_t)gh * 64 + lane;
  float qv = q[idx], kv = k[idx], vv = v[idx];
  float sq = qv * qv, sk = kv * kv;
  #pragma unroll
  for (int m = 1; m < 64; m <<= 1) { sq += __shfl_xor(sq, m); sk += __shfl_xor(sk, m); }
  q[idx] = qv / fmaxf(sqrtf(sq), 1e-12f);
  k[idx] = kv / fmaxf(sqrtf(sk), 1e-12f);
  v[idx] = vv * sigmoidf_(vv);
}

// ---------------- sequential scan: 256 single-wave WGs = (b,h,row-quarter) ----------------
struct StepIn {
  float4 k0, k1, k2, k3, q0, q1, q2, q3;
  float kr, vr, a, bt;
};

__device__ __forceinline__ void scan_load(const float* __restrict__ q, const float* __restrict__ k,
    const float* __restrict__ v, const float* __restrict__ al, const float* __restrict__ be,
    size_t base, size_t ab, int sub16, int d1, StepIn& s) {
  const float* kp = k + base + sub16;
  const float* qp = q + base + sub16;
  s.k0 = *(const float4*)(kp + 0);  s.k1 = *(const float4*)(kp + 4);
  s.k2 = *(const float4*)(kp + 8);  s.k3 = *(const float4*)(kp + 12);
  s.q0 = *(const float4*)(qp + 0);  s.q1 = *(const float4*)(qp + 4);
  s.q2 = *(const float4*)(qp + 8);  s.q3 = *(const float4*)(qp + 12);
  s.kr = k[base + d1];
  s.vr = v[base + d1];
  s.a  = al[ab];
  s.bt = be[ab];
}

__device__ __forceinline__ float scan_step(const StepIn& s, float st[16]) {
  const float c1 = s.a * s.bt * s.kr;   // a*b*k[d1]
  const float c2 = s.bt * s.vr;         // b*v[d1]
  float p = 0.f;
#define GDN_UPD(ii, kv, qv) { st[ii] = fmaf(st[ii], fmaf(-c1, kv, s.a), c2 * (kv)); p = fmaf(st[ii], qv, p); }
  GDN_UPD(0,  s.k0.x, s.q0.x) GDN_UPD(1,  s.k0.y, s.q0.y) GDN_UPD(2,  s.k0.z, s.q0.z) GDN_UPD(3,  s.k0.w, s.q0.w)
  GDN_UPD(4,  s.k1.x, s.q1.x) GDN_UPD(5,  s.k1.y, s.q1.y) GDN_UPD(6,  s.k1.z, s.q1.z) GDN_UPD(7,  s.k1.w, s.q1.w)
  GDN_UPD(8,  s.k2.x, s.q2.x) GDN_UPD(9,  s.k2.y, s.q2.y) GDN_UPD(10, s.k2.z, s.q2.z) GDN_UPD(11, s.k2.w, s.q2.w)
  GDN_UPD(12, s.k3.x, s.q3.x) GDN_UPD(13, s.k3.y, s.q3.y) GDN_UPD(14, s.k3.z, s.q3.z) GDN_UPD(15, s.k3.w, s.q3.w)
#undef GDN_UPD
  return p;
}

__global__ __launch_bounds__(64) void scan_kernel(const float* __restrict__ q, const float* __restrict__ k,
    const float* __restrict__ v, const float* __restrict__ al, const float* __restrict__ be,
    float* __restrict__ o) {
  const int blk = blockIdx.x;            // 0..255
  const int quarter = blk & 3;
  const int h = (blk >> 2) & 15;
  const int b = blk >> 6;
  const int lane = threadIdx.x;
  const int r = lane >> 2, sub = lane & 3, sub16 = sub * 16;
  const int d1 = quarter * 16 + r;
  size_t base = ((size_t)b * Sq * NHq + h) * (size_t)HDq;  // token stride 1024 floats
  size_t ab   = (size_t)b * Sq * NHq + h;                  // token stride 16
  const size_t ob = (size_t)b * Sq * Hq + (size_t)h * HDq + d1;
  float st[16];
  #pragma unroll
  for (int i = 0; i < 16; ++i) st[i] = 0.f;
  StepIn buf[4];
  #pragma unroll
  for (int d = 0; d < 4; ++d)
    scan_load(q, k, v, al, be, base + (size_t)d * 1024, ab + (size_t)d * 16, sub16, d1, buf[d]);
  for (int tb = 0; tb < Sq; tb += 4) {
    #pragma unroll
    for (int d = 0; d < 4; ++d) {
      const int t = tb + d;
      float p = scan_step(buf[d], st);
      p += __shfl_xor(p, 1);
      p += __shfl_xor(p, 2);
      if (sub == 0) o[ob + (size_t)t * Hq] = p;
      const int tn = t + 4;
      if (tn < Sq)
        scan_load(q, k, v, al, be, base + (size_t)tn * 1024, ab + (size_t)tn * 16, sub16, d1, buf[d]);
    }
  }
}

// ---------------- LayerNorm + silu-gate, write bf16 ----------------
__global__ __launch_bounds__(256) void ln_gate_kernel(const float* __restrict__ o, const float* __restrict__ g,
    const float* __restrict__ ln_g, const float* __restrict__ ln_b, u16* __restrict__ y) {
  const int t = blockIdx.x, tid = threadIdx.x;
  const size_t row = (size_t)t * 1024;
  float4 xv = *(const float4*)(o + row + tid * 4);
  float s  = xv.x + xv.y + xv.z + xv.w;
  float s2 = xv.x * xv.x + xv.y * xv.y + xv.z * xv.z + xv.w * xv.w;
  #pragma unroll
  for (int m = 1; m < 64; m <<= 1) { s += __shfl_xor(s, m); s2 += __shfl_xor(s2, m); }
  __shared__ float red[8];
  const int w = tid >> 6, lane = tid & 63;
  if (lane == 0) { red[w] = s; red[4 + w] = s2; }
  __syncthreads();
  s  = red[0] + red[1] + red[2] + red[3];
  s2 = red[4] + red[5] + red[6] + red[7];
  const float mu = s * (1.f / 1024.f);
  const float var = s2 * (1.f / 1024.f) - mu * mu;
  const float rstd = rsqrtf(var + 1e-5f);
  float4 gv = *(const float4*)(g + row + tid * 4);
  float4 lg = *(const float4*)(ln_g + tid * 4);
  float4 lb = *(const float4*)(ln_b + tid * 4);
  ushort4 u;
  u.x = f2bf(((xv.x - mu) * rstd * lg.x + lb.x) * (gv.x * sigmoidf_(gv.x)));
  u.y = f2bf(((xv.y - mu) * rstd * lg.y + lb.y) * (gv.y * sigmoidf_(gv.y)));
  u.z = f2bf(((xv.z - mu) * rstd * lg.z + lb.z) * (gv.z * sigmoidf_(gv.z)));
  u.w = f2bf(((xv.w - mu) * rstd * lg.w + lb.w) * (gv.w * sigmoidf_(gv.w)));
  *(ushort4*)(y + row + tid * 4) = u;
}

extern "C" void kernel_launch(void* const* d_in, const int* in_sizes, int n_in,
                              void* d_out, int out_size, void* d_ws, size_t ws_size,
                              hipStream_t stream) {
  const float* x    = (const float*)d_in[0];
  const float* Wq   = (const float*)d_in[1];
  const float* Wk   = (const float*)d_in[2];
  const float* Wv   = (const float*)d_in[3];
  const float* Wa   = (const float*)d_in[4];
  const float* ba   = (const float*)d_in[5];
  const float* Wb   = (const float*)d_in[6];
  const float* bb   = (const float*)d_in[7];
  const float* Wg   = (const float*)d_in[8];
  const float* Wo   = (const float*)d_in[9];
  const float* ln_g = (const float*)d_in[10];
  const float* ln_b = (const float*)d_in[11];
  float* out = (float*)d_out;
  char* ws = (char*)d_ws;

  u16*   xb = (u16*)(ws + OFF_XB);
  u16*   wb = (u16*)(ws + OFF_WB);
  float* qf = (float*)(ws + OFF_Q);
  float* kf = (float*)(ws + OFF_K);
  float* vf = (float*)(ws + OFF_V);
  float* gf = (float*)(ws + OFF_G);
  float* of = (float*)(ws + OFF_O);
  float* al = (float*)(ws + OFF_AL);
  float* be = (float*)(ws + OFF_BE);
  u16*   yb = (u16*)(ws + OFF_YB);

  // 1) converts: x -> bf16, {Wq,Wk,Wv,Wg,Wo} -> bf16
  cvt_x_kernel<<<8192, 256, 0, stream>>>(x, xb);
  cvt_w_kernel<<<dim3(1024, 1, 5), 256, 0, stream>>>(Wq, Wk, Wv, Wg, Wo, wb);
  // 2) projections q,k,v,g (z = 0..3)
  gemm_bt<<<dim3(64, 8, 4), 256, 0, stream>>>(xb, wb, qf, kf, vf, gf);
  // 3) alpha/beta
  ab_kernel<<<8192, 256, 0, stream>>>(x, Wa, ba, Wb, bb, al, be);
  // 4) l2norm(q,k), silu(v)
  qkv_ep<<<32768, 256, 0, stream>>>(qf, kf, vf);
  // 5) recurrent scan
  scan_kernel<<<256, 64, 0, stream>>>(qf, kf, vf, al, be, of);
  // 6) LN + silu(g) gate -> bf16
  ln_gate_kernel<<<8192, 256, 0, stream>>>(of, gf, ln_g, ln_b, yb);
  // 7) final GEMM: out = y @ Wo^T   (Wo bf16 at wb + 4*1M)
  gemm_bt<<<dim3(64, 8, 1), 256, 0, stream>>>(yb, wb + (size_t)4 * 1024 * 1024, out, out, out, out);
}

// Round 2
// 789.189 us; speedup vs baseline: 1.6480x; 1.6480x over previous
//
#include <hip/hip_runtime.h>

typedef unsigned short u16;
typedef __bf16 bf16x8 __attribute__((ext_vector_type(8)));
typedef float f32x4 __attribute__((ext_vector_type(4)));

constexpr int Bq  = 4;
constexpr int Sq  = 2048;
constexpr int Hq  = 1024;
constexpr int NHq = 16;
constexpr int HDq = 64;
constexpr int CCH = 16;    // chunks
constexpr int LCH = 128;   // chunk length

// workspace layout (bytes, all 256-aligned), total 212,860,928 (same as R1)
constexpr size_t OFF_WB = 0;             // W bf16: 5*1M*2 = 10,485,760
constexpr size_t OFF_XB = 10485760;      // x bf16 16,777,216; REUSED as yb after scan
constexpr size_t OFF_Q  = 27262976;      // q fp32: 33,554,432
constexpr size_t OFF_K  = 60817408;
constexpr size_t OFF_V  = 94371840;
constexpr size_t OFF_G  = 127926272;
constexpr size_t OFF_AL = 161480704;     // alpha: 524,288
constexpr size_t OFF_BE = 162004992;
constexpr size_t OFF_P  = 162529280;     // chunk P products: 64*16*4096*4 = 16,777,216 (becomes s_init)
constexpr size_t OFF_QQ = 179306496;     // chunk Q sums: 16,777,216; REUSED (region is 33.5MB) as `of`
constexpr size_t OFF_O  = 179306496;     // of fp32: 33,554,432 (end 212,860,928)

__device__ __forceinline__ u16 f2bf(float f) {
  unsigned u = __float_as_uint(f);
  u += 0x7fffu + ((u >> 16) & 1u);
  return (u16)(u >> 16);
}
__device__ __forceinline__ float sigmoidf_(float x) { return 1.f / (1.f + __expf(-x)); }

__device__ __forceinline__ void async16(const u16* g, u16* l) {
  __builtin_amdgcn_global_load_lds((const __attribute__((address_space(1))) void*)(const void*)g,
                                   (__attribute__((address_space(3))) void*)(void*)l, 16, 0, 0);
}

// ---------------- converts ----------------
__global__ __launch_bounds__(256) void cvt_x_kernel(const float* __restrict__ in, u16* __restrict__ outp) {
  const size_t i = ((size_t)blockIdx.x * 256 + threadIdx.x) * 4;
  float4 f = *(const float4*)(in + i);
  ushort4 u; u.x = f2bf(f.x); u.y = f2bf(f.y); u.z = f2bf(f.z); u.w = f2bf(f.w);
  *(ushort4*)(outp + i) = u;
}

__global__ __launch_bounds__(256) void cvt_w_kernel(const float* __restrict__ w0, const float* __restrict__ w1,
    const float* __restrict__ w2, const float* __restrict__ w3, const float* __restrict__ w4,
    u16* __restrict__ outp) {
  const int z = blockIdx.z;
  const float* src = (z == 0) ? w0 : (z == 1) ? w1 : (z == 2) ? w2 : (z == 3) ? w3 : w4;
  const size_t i = ((size_t)blockIdx.x * 256 + threadIdx.x) * 4;
  float4 f = *(const float4*)(src + i);
  ushort4 u; u.x = f2bf(f.x); u.y = f2bf(f.y); u.z = f2bf(f.z); u.w = f2bf(f.w);
  *(ushort4*)(outp + (size_t)z * (1024 * 1024) + i) = u;
}

// ---------------- bf16 MFMA GEMM (m97 structure) ----------------
__global__ __launch_bounds__(256) void gemm_bt(const u16* __restrict__ A, const u16* __restrict__ Wb,
    float* __restrict__ C0, float* __restrict__ C1, float* __restrict__ C2, float* __restrict__ C3) {
  constexpr int GK = 1024, GN = 1024;
  __shared__ __align__(16) u16 As[128 * 32];
  __shared__ __align__(16) u16 Bs[128 * 32];
  const int tid = threadIdx.x;
  const int w = tid >> 6, lane = tid & 63;
  const int m0 = blockIdx.x * 128, n0 = blockIdx.y * 128;
  const u16* W = Wb + (size_t)blockIdx.z * (1024 * 1024);
  float* C = (blockIdx.z == 0) ? C0 : (blockIdx.z == 1) ? C1 : (blockIdx.z == 2) ? C2 : C3;
  const int rrow = lane >> 2;
  const int kc8 = (lane & 3) * 8;
  const u16* gA = A + (size_t)(m0 + w * 32 + rrow) * GK + kc8;
  const u16* gB = W + (size_t)(n0 + w * 32 + rrow) * GK + kc8;
  u16* lA = As + (w * 32) * 32;
  u16* lB = Bs + (w * 32) * 32;
  const int qd = lane >> 4, l15 = lane & 15;
  const int wm = (w >> 1) * 64, wn = (w & 1) * 64;
  f32x4 acc[4][4] = {};
  for (int kt = 0; kt < GK; kt += 32) {
    async16(gA,           lA);
    async16(gA + 16 * GK, lA + 16 * 32);
    async16(gB,           lB);
    async16(gB + 16 * GK, lB + 16 * 32);
    gA += 32; gB += 32;
    __syncthreads();
    bf16x8 af[4], bfr[4];
    #pragma unroll
    for (int i = 0; i < 4; ++i) {
      af[i]  = *(const bf16x8*)(As + (wm + i * 16 + l15) * 32 + qd * 8);
      bfr[i] = *(const bf16x8*)(Bs + (wn + i * 16 + l15) * 32 + qd * 8);
    }
    #pragma unroll
    for (int i = 0; i < 4; ++i)
      #pragma unroll
      for (int j = 0; j < 4; ++j)
        acc[i][j] = __builtin_amdgcn_mfma_f32_16x16x32_bf16(af[i], bfr[j], acc[i][j], 0, 0, 0);
    __syncthreads();
  }
  #pragma unroll
  for (int i = 0; i < 4; ++i) {
    const int row = m0 + wm + i * 16 + qd * 4;
    #pragma unroll
    for (int j = 0; j < 4; ++j) {
      const int col = n0 + wn + j * 16 + l15;
      #pragma unroll
      for (int r = 0; r < 4; ++r)
        C[(size_t)(row + r) * GN + col] = acc[i][j][r];
    }
  }
}

// ---------------- alpha/beta ----------------
__global__ __launch_bounds__(256) void ab_kernel(const float* __restrict__ x,
    const float* __restrict__ Wa, const float* __restrict__ ba,
    const float* __restrict__ Wb, const float* __restrict__ bb,
    float* __restrict__ al, float* __restrict__ be) {
  __shared__ __align__(16) float xs[1024];
  const int t = blockIdx.x, tid = threadIdx.x;
  const float4* xp = (const float4*)(x + (size_t)t * 1024);
  ((float4*)xs)[tid] = xp[tid];
  __syncthreads();
  const int o = tid >> 3, p = tid & 7;
  const float* w = (o < 16) ? (Wa + (size_t)o * 1024) : (Wb + (size_t)(o - 16) * 1024);
  float s = 0.f;
  for (int i = p * 128; i < p * 128 + 128; i += 4) {
    float4 xv = *(const float4*)(xs + i);
    float4 wv = *(const float4*)(w + i);
    s += xv.x * wv.x + xv.y * wv.y + xv.z * wv.z + xv.w * wv.w;
  }
  s += __shfl_xor(s, 1); s += __shfl_xor(s, 2); s += __shfl_xor(s, 4);
  if (p == 0) {
    const float bias = (o < 16) ? ba[o] : bb[o - 16];
    const float val = sigmoidf_(s + bias);
    if (o < 16) al[(size_t)t * 16 + o] = val;
    else        be[(size_t)t * 16 + (o - 16)] = val;
  }
}

// ---------------- epilogue: l2norm(q,k), silu(v) ----------------
__global__ __launch_bounds__(256) void qkv_ep(float* __restrict__ q, float* __restrict__ k, float* __restrict__ v) {
  const int gh = blockIdx.x * 4 + (threadIdx.x >> 6);
  const int lane = threadIdx.x & 63;
  const size_t idx = (size_t)gh * 64 + lane;
  float qv = q[idx], kv = k[idx], vv = v[idx];
  float sq = qv * qv, sk = kv * kv;
  #pragma unroll
  for (int m = 1; m < 64; m <<= 1) { sq += __shfl_xor(sq, m); sk += __shfl_xor(sk, m); }
  q[idx] = qv / fmaxf(sqrtf(sq), 1e-12f);
  k[idx] = kv / fmaxf(sqrtf(sk), 1e-12f);
  v[idx] = vv * sigmoidf_(vv);
}

// ================= chunked scan =================
// block = (b, h, chunk): 256 thr = 4 waves (row-quarters). lane: r=lane>>2 (row), sub=lane&3 (16-col group)

struct P1In { float4 k0, k1, k2, k3; float kr, vr, a, bt; };
struct P2In { float4 k0, k1, k2, k3, q0, q1, q2, q3; float kr, vr, a, bt; };

__device__ __forceinline__ void load_p1(const float* __restrict__ k, const float* __restrict__ v,
    const float* __restrict__ al, const float* __restrict__ be,
    size_t base, size_t ab, int sub16, int d1, P1In& s) {
  const float* kp = k + base + sub16;
  s.k0 = *(const float4*)(kp + 0);  s.k1 = *(const float4*)(kp + 4);
  s.k2 = *(const float4*)(kp + 8);  s.k3 = *(const float4*)(kp + 12);
  s.kr = k[base + d1];
  s.vr = v[base + d1];
  s.a  = al[ab];
  s.bt = be[ab];
}

__device__ __forceinline__ void load_p2(const float* __restrict__ q, const float* __restrict__ k,
    const float* __restrict__ v, const float* __restrict__ al, const float* __restrict__ be,
    size_t base, size_t ab, int sub16, int d1, P2In& s) {
  const float* kp = k + base + sub16;
  const float* qp = q + base + sub16;
  s.k0 = *(const float4*)(kp + 0);  s.k1 = *(const float4*)(kp + 4);
  s.k2 = *(const float4*)(kp + 8);  s.k3 = *(const float4*)(kp + 12);
  s.q0 = *(const float4*)(qp + 0);  s.q1 = *(const float4*)(qp + 4);
  s.q2 = *(const float4*)(qp + 8);  s.q3 = *(const float4*)(qp + 12);
  s.kr = k[base + d1];
  s.vr = v[base + d1];
  s.a  = al[ab];
  s.bt = be[ab];
}

// pass 1: compose affine maps over the chunk: state -> P*state + Q
__global__ __launch_bounds__(256) void scan_p1(const float* __restrict__ k, const float* __restrict__ v,
    const float* __restrict__ al, const float* __restrict__ be,
    float* __restrict__ P, float* __restrict__ Q) {
  const int blk = blockIdx.x;               // 0..1023
  const int c = blk & 15;
  const int h = (blk >> 4) & 15;
  const int b = blk >> 8;
  const int w = threadIdx.x >> 6, lane = threadIdx.x & 63;
  const int r = lane >> 2, sub = lane & 3, sub16 = sub * 16;
  const int d1 = w * 16 + r;
  const int t0 = c * LCH;
  const size_t base0 = ((size_t)(b * Sq + t0)) * 1024 + h * 64;
  const size_t ab0   = ((size_t)(b * Sq + t0)) * 16 + h;
  float Pr[16], Qr[16];
  #pragma unroll
  for (int i = 0; i < 16; ++i) { Pr[i] = 1.f; Qr[i] = 0.f; }
  P1In buf[2];
  load_p1(k, v, al, be, base0,        ab0,      sub16, d1, buf[0]);
  load_p1(k, v, al, be, base0 + 1024, ab0 + 16, sub16, d1, buf[1]);
  for (int tb = 0; tb < LCH; tb += 2) {
    #pragma unroll
    for (int d = 0; d < 2; ++d) {
      const P1In& s = buf[d];
      const float c1 = s.a * s.bt * s.kr;
      const float c2 = s.bt * s.vr;
#define GDN_P1(ii, kv) { float A = fmaf(-c1, kv, s.a); Qr[ii] = fmaf(A, Qr[ii], c2 * (kv)); Pr[ii] *= A; }
      GDN_P1(0,  s.k0.x) GDN_P1(1,  s.k0.y) GDN_P1(2,  s.k0.z) GDN_P1(3,  s.k0.w)
      GDN_P1(4,  s.k1.x) GDN_P1(5,  s.k1.y) GDN_P1(6,  s.k1.z) GDN_P1(7,  s.k1.w)
      GDN_P1(8,  s.k2.x) GDN_P1(9,  s.k2.y) GDN_P1(10, s.k2.z) GDN_P1(11, s.k2.w)
      GDN_P1(12, s.k3.x) GDN_P1(13, s.k3.y) GDN_P1(14, s.k3.z) GDN_P1(15, s.k3.w)
#undef GDN_P1
      const int tn = tb + d + 2;   // dead-load past chunk end is benign (stays inside ws)
      load_p1(k, v, al, be, base0 + (size_t)tn * 1024, ab0 + (size_t)tn * 16, sub16, d1, buf[d]);
    }
  }
  const size_t pidx = (((size_t)(b * 16 + h) * CCH + c) * 4096) + (size_t)d1 * 64 + sub16;
  #pragma unroll
  for (int j = 0; j < 4; ++j) {
    *(float4*)(P + pidx + j * 4) = make_float4(Pr[j*4], Pr[j*4+1], Pr[j*4+2], Pr[j*4+3]);
    *(float4*)(Q + pidx + j * 4) = make_float4(Qr[j*4], Qr[j*4+1], Qr[j*4+2], Qr[j*4+3]);
  }
}

// pass 2: sequential combine over chunks; writes chunk-initial state over P
__global__ __launch_bounds__(256) void scan_comb(float* __restrict__ P, const float* __restrict__ Q) {
  const int g = blockIdx.x * 256 + threadIdx.x;  // 0..262143
  const int elem = g & 4095;
  const int bh = g >> 12;
  float s = 0.f;
  for (int c = 0; c < CCH; ++c) {
    const size_t idx = ((size_t)bh * CCH + c) * 4096 + elem;
    const float p = P[idx], qq = Q[idx];
    P[idx] = s;
    s = fmaf(p, s, qq);
  }
}

// pass 3: re-iterate chunk from s_init, emit outputs
__global__ __launch_bounds__(256) void scan_p2(const float* __restrict__ q, const float* __restrict__ k,
    const float* __restrict__ v, const float* __restrict__ al, const float* __restrict__ be,
    const float* __restrict__ Pini, float* __restrict__ o) {
  const int blk = blockIdx.x;
  const int c = blk & 15;
  const int h = (blk >> 4) & 15;
  const int b = blk >> 8;
  const int w = threadIdx.x >> 6, lane = threadIdx.x & 63;
  const int r = lane >> 2, sub = lane & 3, sub16 = sub * 16;
  const int d1 = w * 16 + r;
  const int t0 = c * LCH;
  const size_t base0 = ((size_t)(b * Sq + t0)) * 1024 + h * 64;
  const size_t ab0   = ((size_t)(b * Sq + t0)) * 16 + h;
  const size_t ob0   = base0 + d1;    // out idx for t0; step stride 1024
  const size_t pidx = (((size_t)(b * 16 + h) * CCH + c) * 4096) + (size_t)d1 * 64 + sub16;
  float st[16];
  #pragma unroll
  for (int j = 0; j < 4; ++j) {
    float4 si = *(const float4*)(Pini + pidx + j * 4);
    st[j*4] = si.x; st[j*4+1] = si.y; st[j*4+2] = si.z; st[j*4+3] = si.w;
  }
  P2In buf[2];
  load_p2(q, k, v, al, be, base0,        ab0,      sub16, d1, buf[0]);
  load_p2(q, k, v, al, be, base0 + 1024, ab0 + 16, sub16, d1, buf[1]);
  for (int tb = 0; tb < LCH; tb += 2) {
    #pragma unroll
    for (int d = 0; d < 2; ++d) {
      const int t = tb + d;
      const P2In& s = buf[d];
      const float c1 = s.a * s.bt * s.kr;
      const float c2 = s.bt * s.vr;
      float p0 = 0.f, p1 = 0.f, p2 = 0.f, p3 = 0.f;
#define GDN_P2(ii, kv, qv, pacc) { float A = fmaf(-c1, kv, s.a); st[ii] = fmaf(A, st[ii], c2 * (kv)); pacc = fmaf(st[ii], qv, pacc); }
      GDN_P2(0,  s.k0.x, s.q0.x, p0) GDN_P2(1,  s.k0.y, s.q0.y, p1) GDN_P2(2,  s.k0.z, s.q0.z, p2) GDN_P2(3,  s.k0.w, s.q0.w, p3)
      GDN_P2(4,  s.k1.x, s.q1.x, p0) GDN_P2(5,  s.k1.y, s.q1.y, p1) GDN_P2(6,  s.k1.z, s.q1.z, p2) GDN_P2(7,  s.k1.w, s.q1.w, p3)
      GDN_P2(8,  s.k2.x, s.q2.x, p0) GDN_P2(9,  s.k2.y, s.q2.y, p1) GDN_P2(10, s.k2.z, s.q2.z, p2) GDN_P2(11, s.k2.w, s.q2.w, p3)
      GDN_P2(12, s.k3.x, s.q3.x, p0) GDN_P2(13, s.k3.y, s.q3.y, p1) GDN_P2(14, s.k3.z, s.q3.z, p2) GDN_P2(15, s.k3.w, s.q3.w, p3)
#undef GDN_P2
      float p = (p0 + p1) + (p2 + p3);
      p += __shfl_xor(p, 1);
      p += __shfl_xor(p, 2);
      if (sub == 0) o[ob0 + (size_t)t * 1024] = p;
      const int tn = t + 2;   // dead-load past chunk end is benign
      load_p2(q, k, v, al, be, base0 + (size_t)tn * 1024, ab0 + (size_t)tn * 16, sub16, d1, buf[d]);
    }
  }
}

// ---------------- LayerNorm + silu-gate, write bf16 ----------------
__global__ __launch_bounds__(256) void ln_gate_kernel(const float* __restrict__ o, const float* __restrict__ g,
    const float* __restrict__ ln_g, const float* __restrict__ ln_b, u16* __restrict__ y) {
  const int t = blockIdx.x, tid = threadIdx.x;
  const size_t row = (size_t)t * 1024;
  float4 xv = *(const float4*)(o + row + tid * 4);
  float s  = xv.x + xv.y + xv.z + xv.w;
  float s2 = xv.x * xv.x + xv.y * xv.y + xv.z * xv.z + xv.w * xv.w;
  #pragma unroll
  for (int m = 1; m < 64; m <<= 1) { s += __shfl_xor(s, m); s2 += __shfl_xor(s2, m); }
  __shared__ float red[8];
  const int w = tid >> 6, lane = tid & 63;
  if (lane == 0) { red[w] = s; red[4 + w] = s2; }
  __syncthreads();
  s  = red[0] + red[1] + red[2] + red[3];
  s2 = red[4] + red[5] + red[6] + red[7];
  const float mu = s * (1.f / 1024.f);
  const float var = s2 * (1.f / 1024.f) - mu * mu;
  const float rstd = rsqrtf(var + 1e-5f);
  float4 gv = *(const float4*)(g + row + tid * 4);
  float4 lg = *(const float4*)(ln_g + tid * 4);
  float4 lb = *(const float4*)(ln_b + tid * 4);
  ushort4 u;
  u.x = f2bf(((xv.x - mu) * rstd * lg.x + lb.x) * (gv.x * sigmoidf_(gv.x)));
  u.y = f2bf(((xv.y - mu) * rstd * lg.y + lb.y) * (gv.y * sigmoidf_(gv.y)));
  u.z = f2bf(((xv.z - mu) * rstd * lg.z + lb.z) * (gv.z * sigmoidf_(gv.z)));
  u.w = f2bf(((xv.w - mu) * rstd * lg.w + lb.w) * (gv.w * sigmoidf_(gv.w)));
  *(ushort4*)(y + row + tid * 4) = u;
}

extern "C" void kernel_launch(void* const* d_in, const int* in_sizes, int n_in,
                              void* d_out, int out_size, void* d_ws, size_t ws_size,
                              hipStream_t stream) {
  const float* x    = (const float*)d_in[0];
  const float* Wq   = (const float*)d_in[1];
  const float* Wk   = (const float*)d_in[2];
  const float* Wv   = (const float*)d_in[3];
  const float* Wa   = (const float*)d_in[4];
  const float* ba   = (const float*)d_in[5];
  const float* Wb   = (const float*)d_in[6];
  const float* bb   = (const float*)d_in[7];
  const float* Wg   = (const float*)d_in[8];
  const float* Wo   = (const float*)d_in[9];
  const float* ln_g = (const float*)d_in[10];
  const float* ln_b = (const float*)d_in[11];
  float* out = (float*)d_out;
  char* ws = (char*)d_ws;

  u16*   wb = (u16*)(ws + OFF_WB);
  u16*   xb = (u16*)(ws + OFF_XB);   // becomes yb after scan
  float* qf = (float*)(ws + OFF_Q);
  float* kf = (float*)(ws + OFF_K);
  float* vf = (float*)(ws + OFF_V);
  float* gf = (float*)(ws + OFF_G);
  float* al = (float*)(ws + OFF_AL);
  float* be = (float*)(ws + OFF_BE);
  float* Pb = (float*)(ws + OFF_P);
  float* Qb = (float*)(ws + OFF_QQ);
  float* of = (float*)(ws + OFF_O);  // overlaps Qb (Qb dead after scan_comb)
  u16*   yb = xb;                    // xb dead after projections

  cvt_x_kernel<<<8192, 256, 0, stream>>>(x, xb);
  cvt_w_kernel<<<dim3(1024, 1, 5), 256, 0, stream>>>(Wq, Wk, Wv, Wg, Wo, wb);
  gemm_bt<<<dim3(64, 8, 4), 256, 0, stream>>>(xb, wb, qf, kf, vf, gf);
  ab_kernel<<<8192, 256, 0, stream>>>(x, Wa, ba, Wb, bb, al, be);
  qkv_ep<<<32768, 256, 0, stream>>>(qf, kf, vf);
  // chunked scan
  scan_p1<<<1024, 256, 0, stream>>>(kf, vf, al, be, Pb, Qb);
  scan_comb<<<1024, 256, 0, stream>>>(Pb, Qb);
  scan_p2<<<1024, 256, 0, stream>>>(qf, kf, vf, al, be, Pb, of);
  // epilogue
  ln_gate_kernel<<<8192, 256, 0, stream>>>(of, gf, ln_g, ln_b, yb);
  gemm_bt<<<dim3(64, 8, 1), 256, 0, stream>>>(yb, wb + (size_t)4 * 1024 * 1024, out, out, out, out);
}

// Round 3
// 581.463 us; speedup vs baseline: 2.2368x; 1.3572x over previous
//
#include <hip/hip_runtime.h>

typedef unsigned short u16;
typedef __bf16 bf16x8 __attribute__((ext_vector_type(8)));
typedef float f32x4 __attribute__((ext_vector_type(4)));

constexpr int Bq  = 4;
constexpr int Sq  = 2048;
constexpr int Hq  = 1024;
constexpr int NHq = 16;
constexpr int HDq = 64;
constexpr int CCH = 16;    // chunks
constexpr int LCH = 128;   // chunk length

// workspace layout (bytes), total 212,860,928
constexpr size_t OFF_WB = 0;             // W bf16: 5*1M*2 = 10,485,760
constexpr size_t OFF_XB = 10485760;      // 16,777,216: x-bf16 -> Qc (scan) -> y-bf16 (epilogue)
constexpr size_t OFF_Q  = 27262976;      // q fp32: 33,554,432
constexpr size_t OFF_K  = 60817408;
constexpr size_t OFF_V  = 94371840;
constexpr size_t OFF_G  = 127926272;
constexpr size_t OFF_AL = 161480704;     // alpha: 524,288
constexpr size_t OFF_BE = 162004992;
constexpr size_t OFF_P  = 162529280;     // chunk P: 64*16*4096*4 = 16,777,216 (becomes s_init)
constexpr size_t OFF_O  = 179306496;     // of fp32: 33,554,432 (end 212,860,928)

__device__ __forceinline__ u16 f2bf(float f) {
  unsigned u = __float_as_uint(f);
  u += 0x7fffu + ((u >> 16) & 1u);
  return (u16)(u >> 16);
}
__device__ __forceinline__ float sigmoidf_(float x) { return 1.f / (1.f + __expf(-x)); }

__device__ __forceinline__ void async16(const u16* g, u16* l) {
  __builtin_amdgcn_global_load_lds((const __attribute__((address_space(1))) void*)(const void*)g,
                                   (__attribute__((address_space(3))) void*)(void*)l, 16, 0, 0);
}

// ---------------- converts ----------------
__global__ __launch_bounds__(256) void cvt_x_kernel(const float* __restrict__ in, u16* __restrict__ outp) {
  const size_t i = ((size_t)blockIdx.x * 256 + threadIdx.x) * 4;
  float4 f = *(const float4*)(in + i);
  ushort4 u; u.x = f2bf(f.x); u.y = f2bf(f.y); u.z = f2bf(f.z); u.w = f2bf(f.w);
  *(ushort4*)(outp + i) = u;
}

__global__ __launch_bounds__(256) void cvt_w_kernel(const float* __restrict__ w0, const float* __restrict__ w1,
    const float* __restrict__ w2, const float* __restrict__ w3, const float* __restrict__ w4,
    u16* __restrict__ outp) {
  const int z = blockIdx.z;
  const float* src = (z == 0) ? w0 : (z == 1) ? w1 : (z == 2) ? w2 : (z == 3) ? w3 : w4;
  const size_t i = ((size_t)blockIdx.x * 256 + threadIdx.x) * 4;
  float4 f = *(const float4*)(src + i);
  ushort4 u; u.x = f2bf(f.x); u.y = f2bf(f.y); u.z = f2bf(f.z); u.w = f2bf(f.w);
  *(ushort4*)(outp + (size_t)z * (1024 * 1024) + i) = u;
}

// ---------------- bf16 MFMA GEMM (m97 structure) ----------------
__global__ __launch_bounds__(256) void gemm_bt(const u16* __restrict__ A, const u16* __restrict__ Wb,
    float* __restrict__ C0, float* __restrict__ C1, float* __restrict__ C2, float* __restrict__ C3) {
  constexpr int GK = 1024, GN = 1024;
  __shared__ __align__(16) u16 As[128 * 32];
  __shared__ __align__(16) u16 Bs[128 * 32];
  const int tid = threadIdx.x;
  const int w = tid >> 6, lane = tid & 63;
  const int m0 = blockIdx.x * 128, n0 = blockIdx.y * 128;
  const u16* W = Wb + (size_t)blockIdx.z * (1024 * 1024);
  float* C = (blockIdx.z == 0) ? C0 : (blockIdx.z == 1) ? C1 : (blockIdx.z == 2) ? C2 : C3;
  const int rrow = lane >> 2;
  const int kc8 = (lane & 3) * 8;
  const u16* gA = A + (size_t)(m0 + w * 32 + rrow) * GK + kc8;
  const u16* gB = W + (size_t)(n0 + w * 32 + rrow) * GK + kc8;
  u16* lA = As + (w * 32) * 32;
  u16* lB = Bs + (w * 32) * 32;
  const int qd = lane >> 4, l15 = lane & 15;
  const int wm = (w >> 1) * 64, wn = (w & 1) * 64;
  f32x4 acc[4][4] = {};
  for (int kt = 0; kt < GK; kt += 32) {
    async16(gA,           lA);
    async16(gA + 16 * GK, lA + 16 * 32);
    async16(gB,           lB);
    async16(gB + 16 * GK, lB + 16 * 32);
    gA += 32; gB += 32;
    __syncthreads();
    bf16x8 af[4], bfr[4];
    #pragma unroll
    for (int i = 0; i < 4; ++i) {
      af[i]  = *(const bf16x8*)(As + (wm + i * 16 + l15) * 32 + qd * 8);
      bfr[i] = *(const bf16x8*)(Bs + (wn + i * 16 + l15) * 32 + qd * 8);
    }
    #pragma unroll
    for (int i = 0; i < 4; ++i)
      #pragma unroll
      for (int j = 0; j < 4; ++j)
        acc[i][j] = __builtin_amdgcn_mfma_f32_16x16x32_bf16(af[i], bfr[j], acc[i][j], 0, 0, 0);
    __syncthreads();
  }
  #pragma unroll
  for (int i = 0; i < 4; ++i) {
    const int row = m0 + wm + i * 16 + qd * 4;
    #pragma unroll
    for (int j = 0; j < 4; ++j) {
      const int col = n0 + wn + j * 16 + l15;
      #pragma unroll
      for (int r = 0; r < 4; ++r)
        C[(size_t)(row + r) * GN + col] = acc[i][j][r];
    }
  }
}

// ---------------- alpha/beta ----------------
__global__ __launch_bounds__(256) void ab_kernel(const float* __restrict__ x,
    const float* __restrict__ Wa, const float* __restrict__ ba,
    const float* __restrict__ Wb, const float* __restrict__ bb,
    float* __restrict__ al, float* __restrict__ be) {
  __shared__ __align__(16) float xs[1024];
  const int t = blockIdx.x, tid = threadIdx.x;
  const float4* xp = (const float4*)(x + (size_t)t * 1024);
  ((float4*)xs)[tid] = xp[tid];
  __syncthreads();
  const int o = tid >> 3, p = tid & 7;
  const float* w = (o < 16) ? (Wa + (size_t)o * 1024) : (Wb + (size_t)(o - 16) * 1024);
  float s = 0.f;
  for (int i = p * 128; i < p * 128 + 128; i += 4) {
    float4 xv = *(const float4*)(xs + i);
    float4 wv = *(const float4*)(w + i);
    s += xv.x * wv.x + xv.y * wv.y + xv.z * wv.z + xv.w * wv.w;
  }
  s += __shfl_xor(s, 1); s += __shfl_xor(s, 2); s += __shfl_xor(s, 4);
  if (p == 0) {
    const float bias = (o < 16) ? ba[o] : bb[o - 16];
    const float val = sigmoidf_(s + bias);
    if (o < 16) al[(size_t)t * 16 + o] = val;
    else        be[(size_t)t * 16 + (o - 16)] = val;
  }
}

// ---------------- epilogue: l2norm(q,k), silu(v) ----------------
__global__ __launch_bounds__(256) void qkv_ep(float* __restrict__ q, float* __restrict__ k, float* __restrict__ v) {
  const int gh = blockIdx.x * 4 + (threadIdx.x >> 6);
  const int lane = threadIdx.x & 63;
  const size_t idx = (size_t)gh * 64 + lane;
  float qv = q[idx], kv = k[idx], vv = v[idx];
  float sq = qv * qv, sk = kv * kv;
  #pragma unroll
  for (int m = 1; m < 64; m <<= 1) { sq += __shfl_xor(sq, m); sk += __shfl_xor(sk, m); }
  q[idx] = qv / fmaxf(sqrtf(sq), 1e-12f);
  k[idx] = kv / fmaxf(sqrtf(sk), 1e-12f);
  v[idx] = vv * sigmoidf_(vv);
}

// ================= chunked scan, 8x8 register tile per lane =================
// One wave owns one (b,h,chunk): lane = r_blk*8 + c_blk; lane holds rows r_blk*8..+7 x cols c_blk*8..+7.
// Per-lane per-step inputs: kc[8] (cols), qc[8], kr[8] (rows), vr[8], wave-uniform a,bt.

struct S1 { float4 kc0, kc1, kr0, kr1, vr0, vr1; float a, bt; };
struct S2 { float4 kc0, kc1, qc0, qc1, kr0, kr1, vr0, vr1; float a, bt; };

__device__ __forceinline__ void load_s1(const float* __restrict__ k, const float* __restrict__ v,
    const float* __restrict__ al, const float* __restrict__ be,
    size_t base, size_t ab, int c8, int r8, S1& s) {
  s.kc0 = *(const float4*)(k + base + c8);     s.kc1 = *(const float4*)(k + base + c8 + 4);
  s.kr0 = *(const float4*)(k + base + r8);     s.kr1 = *(const float4*)(k + base + r8 + 4);
  s.vr0 = *(const float4*)(v + base + r8);     s.vr1 = *(const float4*)(v + base + r8 + 4);
  s.a = al[ab]; s.bt = be[ab];
}

__device__ __forceinline__ void load_s2(const float* __restrict__ q, const float* __restrict__ k,
    const float* __restrict__ v, const float* __restrict__ al, const float* __restrict__ be,
    size_t base, size_t ab, int c8, int r8, S2& s) {
  s.kc0 = *(const float4*)(k + base + c8);     s.kc1 = *(const float4*)(k + base + c8 + 4);
  s.qc0 = *(const float4*)(q + base + c8);     s.qc1 = *(const float4*)(q + base + c8 + 4);
  s.kr0 = *(const float4*)(k + base + r8);     s.kr1 = *(const float4*)(k + base + r8 + 4);
  s.vr0 = *(const float4*)(v + base + r8);     s.vr1 = *(const float4*)(v + base + r8 + 4);
  s.a = al[ab]; s.bt = be[ab];
}

// pass 1: compose affine maps over the chunk
__global__ __launch_bounds__(256) void scan_p1(const float* __restrict__ k, const float* __restrict__ v,
    const float* __restrict__ al, const float* __restrict__ be,
    float* __restrict__ P, float* __restrict__ Q) {
  const int w = threadIdx.x >> 6, lane = threadIdx.x & 63;
  const int g = blockIdx.x * 4 + w;          // 0..1023
  const int c = g & 15;
  const int bh = g >> 4;                      // b*16+h
  const int b = bh >> 4, h = bh & 15;
  const int r8 = (lane >> 3) * 8, c8 = (lane & 7) * 8;
  const int t0 = c * LCH;
  const size_t base0 = ((size_t)(b * Sq + t0)) * 1024 + h * 64;
  const size_t ab0   = ((size_t)(b * Sq + t0)) * 16 + h;
  float Pr[64], Qr[64];
  #pragma unroll
  for (int i = 0; i < 64; ++i) { Pr[i] = 1.f; Qr[i] = 0.f; }
  S1 buf[2];
  load_s1(k, v, al, be, base0,        ab0,      c8, r8, buf[0]);
  load_s1(k, v, al, be, base0 + 1024, ab0 + 16, c8, r8, buf[1]);
  for (int tb = 0; tb < LCH; tb += 2) {
    #pragma unroll
    for (int d = 0; d < 2; ++d) {
      const S1 s = buf[d];
      const int tn = tb + d + 2;   // dead-load past chunk end stays inside ws: benign
      load_s1(k, v, al, be, base0 + (size_t)tn * 1024, ab0 + (size_t)tn * 16, c8, r8, buf[d]);
      const float kcv[8] = {s.kc0.x, s.kc0.y, s.kc0.z, s.kc0.w, s.kc1.x, s.kc1.y, s.kc1.z, s.kc1.w};
      const float krv[8] = {s.kr0.x, s.kr0.y, s.kr0.z, s.kr0.w, s.kr1.x, s.kr1.y, s.kr1.z, s.kr1.w};
      const float vrv[8] = {s.vr0.x, s.vr0.y, s.vr0.z, s.vr0.w, s.vr1.x, s.vr1.y, s.vr1.z, s.vr1.w};
      const float abt = s.a * s.bt;
      float c1[8], c2[8];
      #pragma unroll
      for (int i = 0; i < 8; ++i) { c1[i] = abt * krv[i]; c2[i] = s.bt * vrv[i]; }
      #pragma unroll
      for (int i = 0; i < 8; ++i)
        #pragma unroll
        for (int j = 0; j < 8; ++j) {
          const int e = i * 8 + j;
          const float A = fmaf(-c1[i], kcv[j], s.a);
          Qr[e] = fmaf(A, Qr[e], c2[i] * kcv[j]);
          Pr[e] *= A;
        }
    }
  }
  const size_t pbase = ((size_t)bh * CCH + c) * 4096 + (size_t)c8;
  #pragma unroll
  for (int i = 0; i < 8; ++i) {
    const size_t pi = pbase + (size_t)(r8 + i) * 64;
    *(float4*)(P + pi)     = make_float4(Pr[i*8],   Pr[i*8+1], Pr[i*8+2], Pr[i*8+3]);
    *(float4*)(P + pi + 4) = make_float4(Pr[i*8+4], Pr[i*8+5], Pr[i*8+6], Pr[i*8+7]);
    *(float4*)(Q + pi)     = make_float4(Qr[i*8],   Qr[i*8+1], Qr[i*8+2], Qr[i*8+3]);
    *(float4*)(Q + pi + 4) = make_float4(Qr[i*8+4], Qr[i*8+5], Qr[i*8+6], Qr[i*8+7]);
  }
}

// pass 2: sequential combine over chunks; writes chunk-initial state over P
__global__ __launch_bounds__(256) void scan_comb(float* __restrict__ P, const float* __restrict__ Q) {
  const int g = blockIdx.x * 256 + threadIdx.x;  // 0..262143
  const int elem = g & 4095;
  const int bh = g >> 12;
  float s = 0.f;
  for (int c = 0; c < CCH; ++c) {
    const size_t idx = ((size_t)bh * CCH + c) * 4096 + elem;
    const float p = P[idx], qq = Q[idx];
    P[idx] = s;
    s = fmaf(p, s, qq);
  }
}

// pass 3: re-iterate chunk from s_init, emit outputs
__global__ __launch_bounds__(256) void scan_p2(const float* __restrict__ q, const float* __restrict__ k,
    const float* __restrict__ v, const float* __restrict__ al, const float* __restrict__ be,
    const float* __restrict__ Pini, float* __restrict__ o) {
  const int w = threadIdx.x >> 6, lane = threadIdx.x & 63;
  const int g = blockIdx.x * 4 + w;
  const int c = g & 15;
  const int bh = g >> 4;
  const int b = bh >> 4, h = bh & 15;
  const int cb = lane & 7;
  const int r8 = (lane >> 3) * 8, c8 = cb * 8;
  const int t0 = c * LCH;
  const size_t base0 = ((size_t)(b * Sq + t0)) * 1024 + h * 64;
  const size_t ab0   = ((size_t)(b * Sq + t0)) * 16 + h;
  const size_t pbase = ((size_t)bh * CCH + c) * 4096 + (size_t)c8;
  float st[64];
  #pragma unroll
  for (int i = 0; i < 8; ++i) {
    float4 s0 = *(const float4*)(Pini + pbase + (size_t)(r8 + i) * 64);
    float4 s1 = *(const float4*)(Pini + pbase + (size_t)(r8 + i) * 64 + 4);
    st[i*8]   = s0.x; st[i*8+1] = s0.y; st[i*8+2] = s0.z; st[i*8+3] = s0.w;
    st[i*8+4] = s1.x; st[i*8+5] = s1.y; st[i*8+6] = s1.z; st[i*8+7] = s1.w;
  }
  S2 buf[2];
  load_s2(q, k, v, al, be, base0,        ab0,      c8, r8, buf[0]);
  load_s2(q, k, v, al, be, base0 + 1024, ab0 + 16, c8, r8, buf[1]);
  const bool hi4 = (cb & 4), hi2 = (cb & 2), hi1 = (cb & 1);
  for (int tb = 0; tb < LCH; tb += 2) {
    #pragma unroll
    for (int d = 0; d < 2; ++d) {
      const int t = tb + d;
      const S2 s = buf[d];
      const int tn = t + 2;        // dead-load past chunk end: benign
      load_s2(q, k, v, al, be, base0 + (size_t)tn * 1024, ab0 + (size_t)tn * 16, c8, r8, buf[d]);
      const float kcv[8] = {s.kc0.x, s.kc0.y, s.kc0.z, s.kc0.w, s.kc1.x, s.kc1.y, s.kc1.z, s.kc1.w};
      const float qcv[8] = {s.qc0.x, s.qc0.y, s.qc0.z, s.qc0.w, s.qc1.x, s.qc1.y, s.qc1.z, s.qc1.w};
      const float krv[8] = {s.kr0.x, s.kr0.y, s.kr0.z, s.kr0.w, s.kr1.x, s.kr1.y, s.kr1.z, s.kr1.w};
      const float vrv[8] = {s.vr0.x, s.vr0.y, s.vr0.z, s.vr0.w, s.vr1.x, s.vr1.y, s.vr1.z, s.vr1.w};
      const float abt = s.a * s.bt;
      float c1[8], c2[8];
      #pragma unroll
      for (int i = 0; i < 8; ++i) { c1[i] = abt * krv[i]; c2[i] = s.bt * vrv[i]; }
      float p[8];
      #pragma unroll
      for (int i = 0; i < 8; ++i) p[i] = 0.f;
      #pragma unroll
      for (int i = 0; i < 8; ++i)
        #pragma unroll
        for (int j = 0; j < 8; ++j) {
          const int e = i * 8 + j;
          const float A = fmaf(-c1[i], kcv[j], s.a);
          st[e] = fmaf(A, st[e], c2[i] * kcv[j]);
          p[i] = fmaf(st[e], qcv[j], p[i]);
        }
      // reduce-scatter across c_blk: 3 stages; lane (r_blk, cb) ends with row r8+cb total
      float r4[4];
      #pragma unroll
      for (int i = 0; i < 4; ++i) {
        const float send = hi4 ? p[i] : p[i + 4];
        const float recv = __shfl_xor(send, 4);
        r4[i] = (hi4 ? p[i + 4] : p[i]) + recv;
      }
      float r2[2];
      #pragma unroll
      for (int i = 0; i < 2; ++i) {
        const float send = hi2 ? r4[i] : r4[i + 2];
        const float recv = __shfl_xor(send, 2);
        r2[i] = (hi2 ? r4[i + 2] : r4[i]) + recv;
      }
      {
        const float send = hi1 ? r2[0] : r2[1];
        const float recv = __shfl_xor(send, 1);
        const float tot = (hi1 ? r2[1] : r2[0]) + recv;
        o[base0 + (size_t)t * 1024 + lane] = tot;
      }
    }
  }
}

// ---------------- LayerNorm + silu-gate, write bf16 ----------------
__global__ __launch_bounds__(256) void ln_gate_kernel(const float* __restrict__ o, const float* __restrict__ g,
    const float* __restrict__ ln_g, const float* __restrict__ ln_b, u16* __restrict__ y) {
  const int t = blockIdx.x, tid = threadIdx.x;
  const size_t row = (size_t)t * 1024;
  float4 xv = *(const float4*)(o + row + tid * 4);
  float s  = xv.x + xv.y + xv.z + xv.w;
  float s2 = xv.x * xv.x + xv.y * xv.y + xv.z * xv.z + xv.w * xv.w;
  #pragma unroll
  for (int m = 1; m < 64; m <<= 1) { s += __shfl_xor(s, m); s2 += __shfl_xor(s2, m); }
  __shared__ float red[8];
  const int w = tid >> 6, lane = tid & 63;
  if (lane == 0) { red[w] = s; red[4 + w] = s2; }
  __syncthreads();
  s  = red[0] + red[1] + red[2] + red[3];
  s2 = red[4] + red[5] + red[6] + red[7];
  const float mu = s * (1.f / 1024.f);
  const float var = s2 * (1.f / 1024.f) - mu * mu;
  const float rstd = rsqrtf(var + 1e-5f);
  float4 gv = *(const float4*)(g + row + tid * 4);
  float4 lg = *(const float4*)(ln_g + tid * 4);
  float4 lb = *(const float4*)(ln_b + tid * 4);
  ushort4 u;
  u.x = f2bf(((xv.x - mu) * rstd * lg.x + lb.x) * (gv.x * sigmoidf_(gv.x)));
  u.y = f2bf(((xv.y - mu) * rstd * lg.y + lb.y) * (gv.y * sigmoidf_(gv.y)));
  u.z = f2bf(((xv.z - mu) * rstd * lg.z + lb.z) * (gv.z * sigmoidf_(gv.z)));
  u.w = f2bf(((xv.w - mu) * rstd * lg.w + lb.w) * (gv.w * sigmoidf_(gv.w)));
  *(ushort4*)(y + row + tid * 4) = u;
}

extern "C" void kernel_launch(void* const* d_in, const int* in_sizes, int n_in,
                              void* d_out, int out_size, void* d_ws, size_t ws_size,
                              hipStream_t stream) {
  const float* x    = (const float*)d_in[0];
  const float* Wq   = (const float*)d_in[1];
  const float* Wk   = (const float*)d_in[2];
  const float* Wv   = (const float*)d_in[3];
  const float* Wa   = (const float*)d_in[4];
  const float* ba   = (const float*)d_in[5];
  const float* Wb   = (const float*)d_in[6];
  const float* bb   = (const float*)d_in[7];
  const float* Wg   = (const float*)d_in[8];
  const float* Wo   = (const float*)d_in[9];
  const float* ln_g = (const float*)d_in[10];
  const float* ln_b = (const float*)d_in[11];
  float* out = (float*)d_out;
  char* ws = (char*)d_ws;

  u16*   wb = (u16*)(ws + OFF_WB);
  u16*   xb = (u16*)(ws + OFF_XB);   // x-bf16 -> Qc -> y-bf16
  float* qf = (float*)(ws + OFF_Q);
  float* kf = (float*)(ws + OFF_K);
  float* vf = (float*)(ws + OFF_V);
  float* gf = (float*)(ws + OFF_G);
  float* al = (float*)(ws + OFF_AL);
  float* be = (float*)(ws + OFF_BE);
  float* Pb = (float*)(ws + OFF_P);
  float* Qc = (float*)(ws + OFF_XB); // reuses dead x-bf16 region (16 MB, exact fit)
  float* of = (float*)(ws + OFF_O);
  u16*   yb = xb;                    // Qc dead after scan_comb

  cvt_x_kernel<<<8192, 256, 0, stream>>>(x, xb);
  cvt_w_kernel<<<dim3(1024, 1, 5), 256, 0, stream>>>(Wq, Wk, Wv, Wg, Wo, wb);
  gemm_bt<<<dim3(64, 8, 4), 256, 0, stream>>>(xb, wb, qf, kf, vf, gf);
  ab_kernel<<<8192, 256, 0, stream>>>(x, Wa, ba, Wb, bb, al, be);
  qkv_ep<<<32768, 256, 0, stream>>>(qf, kf, vf);
  // chunked scan (8x8 tile per lane, 1 wave per (b,h,chunk))
  scan_p1<<<256, 256, 0, stream>>>(kf, vf, al, be, Pb, Qc);
  scan_comb<<<1024, 256, 0, stream>>>(Pb, Qc);
  scan_p2<<<256, 256, 0, stream>>>(qf, kf, vf, al, be, Pb, of);
  // epilogue
  ln_gate_kernel<<<8192, 256, 0, stream>>>(of, gf, ln_g, ln_b, yb);
  gemm_bt<<<dim3(64, 8, 1), 256, 0, stream>>>(yb, wb + (size_t)4 * 1024 * 1024, out, out, out, out);
}

// Round 4
// 453.679 us; speedup vs baseline: 2.8668x; 1.2817x over previous
//
#include <hip/hip_runtime.h>

typedef unsigned short u16;
typedef __bf16 bf16x8 __attribute__((ext_vector_type(8)));
typedef float f32x4 __attribute__((ext_vector_type(4)));

constexpr int Bq  = 4;
constexpr int Sq  = 2048;
constexpr int Hq  = 1024;
constexpr int NHq = 16;
constexpr int HDq = 64;
constexpr int CCH = 16;    // chunks
constexpr int LCH = 128;   // chunk length

// workspace layout (bytes), total 212,860,928 (unchanged from R1-R3)
constexpr size_t OFF_WB = 0;             // W bf16: 5*1M*2 = 10,485,760
constexpr size_t OFF_XB = 10485760;      // 16,777,216: x-bf16 -> Qc (scan) -> y-bf16 (epilogue)
constexpr size_t OFF_Q  = 27262976;      // q fp32: 33,554,432
constexpr size_t OFF_K  = 60817408;
constexpr size_t OFF_V  = 94371840;
constexpr size_t OFF_G  = 127926272;
constexpr size_t OFF_AL = 161480704;     // alpha: 524,288
constexpr size_t OFF_BE = 162004992;
constexpr size_t OFF_P  = 162529280;     // Wab bf16 (256 KB) during GEMM -> chunk P (16 MB) during scan
constexpr size_t OFF_O  = 179306496;     // of fp32: 33,554,432 (end 212,860,928)

__device__ __forceinline__ u16 f2bf(float f) {
  unsigned u = __float_as_uint(f);
  u += 0x7fffu + ((u >> 16) & 1u);
  return (u16)(u >> 16);
}
__device__ __forceinline__ float sigmoidf_(float x) { return 1.f / (1.f + __expf(-x)); }

__device__ __forceinline__ void async16(const u16* g, u16* l) {
  __builtin_amdgcn_global_load_lds((const __attribute__((address_space(1))) void*)(const void*)g,
                                   (__attribute__((address_space(3))) void*)(void*)l, 16, 0, 0);
}

// ---------------- converts ----------------
__global__ __launch_bounds__(256) void cvt_x_kernel(const float* __restrict__ in, u16* __restrict__ outp) {
  const size_t i = ((size_t)blockIdx.x * 256 + threadIdx.x) * 4;
  float4 f = *(const float4*)(in + i);
  ushort4 u; u.x = f2bf(f.x); u.y = f2bf(f.y); u.z = f2bf(f.z); u.w = f2bf(f.w);
  *(ushort4*)(outp + i) = u;
}

__global__ __launch_bounds__(256) void cvt_w_kernel(const float* __restrict__ w0, const float* __restrict__ w1,
    const float* __restrict__ w2, const float* __restrict__ w3, const float* __restrict__ w4,
    u16* __restrict__ outp) {
  const int z = blockIdx.z;
  const float* src = (z == 0) ? w0 : (z == 1) ? w1 : (z == 2) ? w2 : (z == 3) ? w3 : w4;
  const size_t i = ((size_t)blockIdx.x * 256 + threadIdx.x) * 4;
  float4 f = *(const float4*)(src + i);
  ushort4 u; u.x = f2bf(f.x); u.y = f2bf(f.y); u.z = f2bf(f.z); u.w = f2bf(f.w);
  *(ushort4*)(outp + (size_t)z * (1024 * 1024) + i) = u;
}

// Wab: 128x1024 bf16; rows 0..15 = Wa, 16..31 = Wb, rest zero
__global__ __launch_bounds__(256) void cvt_ab_kernel(const float* __restrict__ Wa, const float* __restrict__ Wb,
    u16* __restrict__ outp) {
  const size_t i = ((size_t)blockIdx.x * 256 + threadIdx.x) * 4;
  const int row = (int)(i >> 10);
  ushort4 u;
  if (row < 32) {
    const float* src = (row < 16) ? (Wa + i) : (Wb + i - 16 * 1024);
    float4 f = *(const float4*)src;
    u.x = f2bf(f.x); u.y = f2bf(f.y); u.z = f2bf(f.z); u.w = f2bf(f.w);
  } else {
    u.x = u.y = u.z = u.w = 0;
  }
  *(ushort4*)(outp + i) = u;
}

// ---------------- bf16 MFMA GEMM (m97 structure) with fused epilogues ----------------
// mode 0: plain store to Cq.
// mode 1: z=0 q(l2norm), z=1 k(l2norm), z=2 v(silu), z=3 g(plain), z=4 alpha/beta(sigmoid+bias, y==0 only)
__global__ __launch_bounds__(256) void gemm_bt(const u16* __restrict__ A, const u16* __restrict__ Wall,
    const u16* __restrict__ Wab,
    float* __restrict__ Cq, float* __restrict__ Ck, float* __restrict__ Cv, float* __restrict__ Cg,
    float* __restrict__ al, float* __restrict__ be,
    const float* __restrict__ ba, const float* __restrict__ bb, int mode) {
  constexpr int GK = 1024, GN = 1024;
  const int z = blockIdx.z;
  if (mode == 1 && z == 4 && blockIdx.y > 0) return;
  __shared__ __align__(16) u16 As[128 * 32];
  __shared__ __align__(16) u16 Bs[128 * 32];
  const int tid = threadIdx.x;
  const int w = tid >> 6, lane = tid & 63;
  const int m0 = blockIdx.x * 128, n0 = blockIdx.y * 128;
  const u16* W = (mode == 1 && z == 4) ? Wab : (Wall + (size_t)z * (1024 * 1024));
  const int rrow = lane >> 2;
  const int kc8 = (lane & 3) * 8;
  const u16* gA = A + (size_t)(m0 + w * 32 + rrow) * GK + kc8;
  const u16* gB = W + (size_t)(n0 + w * 32 + rrow) * GK + kc8;
  u16* lA = As + (w * 32) * 32;
  u16* lB = Bs + (w * 32) * 32;
  const int qd = lane >> 4, l15 = lane & 15;
  const int wm = (w >> 1) * 64, wn = (w & 1) * 64;
  f32x4 acc[4][4] = {};
  for (int kt = 0; kt < GK; kt += 32) {
    async16(gA,           lA);
    async16(gA + 16 * GK, lA + 16 * 32);
    async16(gB,           lB);
    async16(gB + 16 * GK, lB + 16 * 32);
    gA += 32; gB += 32;
    __syncthreads();
    bf16x8 af[4], bfr[4];
    #pragma unroll
    for (int i = 0; i < 4; ++i) {
      af[i]  = *(const bf16x8*)(As + (wm + i * 16 + l15) * 32 + qd * 8);
      bfr[i] = *(const bf16x8*)(Bs + (wn + i * 16 + l15) * 32 + qd * 8);
    }
    #pragma unroll
    for (int i = 0; i < 4; ++i)
      #pragma unroll
      for (int j = 0; j < 4; ++j)
        acc[i][j] = __builtin_amdgcn_mfma_f32_16x16x32_bf16(af[i], bfr[j], acc[i][j], 0, 0, 0);
    __syncthreads();
  }
  // ---- epilogues ---- C/D layout: col = l15, row = qd*4 + reg
  if (mode == 1 && z == 4) {
    // alpha/beta: cols 0..15 = alpha, 16..31 = beta (waves with wn==64 have nothing)
    if (wn == 0) {
      const float bav = ba[l15], bbv = bb[l15];
      #pragma unroll
      for (int i = 0; i < 4; ++i) {
        const int row = m0 + wm + i * 16 + qd * 4;
        #pragma unroll
        for (int r = 0; r < 4; ++r) {
          al[(size_t)(row + r) * 16 + l15] = sigmoidf_(acc[i][0][r] + bav);
          be[(size_t)(row + r) * 16 + l15] = sigmoidf_(acc[i][1][r] + bbv);
        }
      }
    }
    return;
  }
  if (mode == 1 && (z == 0 || z == 1)) {
    // l2norm across this wave's 64-col head: frag-sum + shfl over the 16 l15-lanes
    #pragma unroll
    for (int i = 0; i < 4; ++i)
      #pragma unroll
      for (int r = 0; r < 4; ++r) {
        float ss = acc[i][0][r] * acc[i][0][r] + acc[i][1][r] * acc[i][1][r]
                 + acc[i][2][r] * acc[i][2][r] + acc[i][3][r] * acc[i][3][r];
        ss += __shfl_xor(ss, 1); ss += __shfl_xor(ss, 2);
        ss += __shfl_xor(ss, 4); ss += __shfl_xor(ss, 8);
        const float rn = 1.f / fmaxf(sqrtf(ss), 1e-12f);
        acc[i][0][r] *= rn; acc[i][1][r] *= rn; acc[i][2][r] *= rn; acc[i][3][r] *= rn;
      }
  } else if (mode == 1 && z == 2) {
    #pragma unroll
    for (int i = 0; i < 4; ++i)
      #pragma unroll
      for (int j = 0; j < 4; ++j)
        #pragma unroll
        for (int r = 0; r < 4; ++r)
          acc[i][j][r] = acc[i][j][r] * sigmoidf_(acc[i][j][r]);
  }
  float* C = (mode == 0) ? Cq : ((z == 0) ? Cq : (z == 1) ? Ck : (z == 2) ? Cv : Cg);
  #pragma unroll
  for (int i = 0; i < 4; ++i) {
    const int row = m0 + wm + i * 16 + qd * 4;
    #pragma unroll
    for (int j = 0; j < 4; ++j) {
      const int col = n0 + wn + j * 16 + l15;
      #pragma unroll
      for (int r = 0; r < 4; ++r)
        C[(size_t)(row + r) * GN + col] = acc[i][j][r];
    }
  }
}

// ================= chunked scan, 8x8 register tile per lane =================
struct S1 { float4 kc0, kc1, kr0, kr1, vr0, vr1; float a, bt; };
struct S2 { float4 kc0, kc1, qc0, qc1, kr0, kr1, vr0, vr1; float a, bt; };

__device__ __forceinline__ void load_s1(const float* __restrict__ k, const float* __restrict__ v,
    const float* __restrict__ al, const float* __restrict__ be,
    size_t base, size_t ab, int c8, int r8, S1& s) {
  s.kc0 = *(const float4*)(k + base + c8);     s.kc1 = *(const float4*)(k + base + c8 + 4);
  s.kr0 = *(const float4*)(k + base + r8);     s.kr1 = *(const float4*)(k + base + r8 + 4);
  s.vr0 = *(const float4*)(v + base + r8);     s.vr1 = *(const float4*)(v + base + r8 + 4);
  s.a = al[ab]; s.bt = be[ab];
}

__device__ __forceinline__ void load_s2(const float* __restrict__ q, const float* __restrict__ k,
    const float* __restrict__ v, const float* __restrict__ al, const float* __restrict__ be,
    size_t base, size_t ab, int c8, int r8, S2& s) {
  s.kc0 = *(const float4*)(k + base + c8);     s.kc1 = *(const float4*)(k + base + c8 + 4);
  s.qc0 = *(const float4*)(q + base + c8);     s.qc1 = *(const float4*)(q + base + c8 + 4);
  s.kr0 = *(const float4*)(k + base + r8);     s.kr1 = *(const float4*)(k + base + r8 + 4);
  s.vr0 = *(const float4*)(v + base + r8);     s.vr1 = *(const float4*)(v + base + r8 + 4);
  s.a = al[ab]; s.bt = be[ab];
}

// pass 1: compose affine maps over the chunk
__global__ __launch_bounds__(256) void scan_p1(const float* __restrict__ k, const float* __restrict__ v,
    const float* __restrict__ al, const float* __restrict__ be,
    float* __restrict__ P, float* __restrict__ Q) {
  const int w = threadIdx.x >> 6, lane = threadIdx.x & 63;
  const int g = blockIdx.x * 4 + w;          // 0..1023
  const int c = g & 15;
  const int bh = g >> 4;
  const int b = bh >> 4, h = bh & 15;
  const int r8 = (lane >> 3) * 8, c8 = (lane & 7) * 8;
  const int t0 = c * LCH;
  const size_t base0 = ((size_t)(b * Sq + t0)) * 1024 + h * 64;
  const size_t ab0   = ((size_t)(b * Sq + t0)) * 16 + h;
  float Pr[64], Qr[64];
  #pragma unroll
  for (int i = 0; i < 64; ++i) { Pr[i] = 1.f; Qr[i] = 0.f; }
  S1 buf[2];
  load_s1(k, v, al, be, base0,        ab0,      c8, r8, buf[0]);
  load_s1(k, v, al, be, base0 + 1024, ab0 + 16, c8, r8, buf[1]);
  for (int tb = 0; tb < LCH; tb += 2) {
    #pragma unroll
    for (int d = 0; d < 2; ++d) {
      const S1 s = buf[d];
      const int tn = tb + d + 2;   // dead-load past chunk end stays inside ws: benign
      load_s1(k, v, al, be, base0 + (size_t)tn * 1024, ab0 + (size_t)tn * 16, c8, r8, buf[d]);
      const float kcv[8] = {s.kc0.x, s.kc0.y, s.kc0.z, s.kc0.w, s.kc1.x, s.kc1.y, s.kc1.z, s.kc1.w};
      const float krv[8] = {s.kr0.x, s.kr0.y, s.kr0.z, s.kr0.w, s.kr1.x, s.kr1.y, s.kr1.z, s.kr1.w};
      const float vrv[8] = {s.vr0.x, s.vr0.y, s.vr0.z, s.vr0.w, s.vr1.x, s.vr1.y, s.vr1.z, s.vr1.w};
      const float abt = s.a * s.bt;
      float c1[8], c2[8];
      #pragma unroll
      for (int i = 0; i < 8; ++i) { c1[i] = abt * krv[i]; c2[i] = s.bt * vrv[i]; }
      #pragma unroll
      for (int i = 0; i < 8; ++i)
        #pragma unroll
        for (int j = 0; j < 8; ++j) {
          const int e = i * 8 + j;
          const float A = fmaf(-c1[i], kcv[j], s.a);
          Qr[e] = fmaf(A, Qr[e], c2[i] * kcv[j]);
          Pr[e] *= A;
        }
    }
  }
  const size_t pbase = ((size_t)bh * CCH + c) * 4096 + (size_t)c8;
  #pragma unroll
  for (int i = 0; i < 8; ++i) {
    const size_t pi = pbase + (size_t)(r8 + i) * 64;
    *(float4*)(P + pi)     = make_float4(Pr[i*8],   Pr[i*8+1], Pr[i*8+2], Pr[i*8+3]);
    *(float4*)(P + pi + 4) = make_float4(Pr[i*8+4], Pr[i*8+5], Pr[i*8+6], Pr[i*8+7]);
    *(float4*)(Q + pi)     = make_float4(Qr[i*8],   Qr[i*8+1], Qr[i*8+2], Qr[i*8+3]);
    *(float4*)(Q + pi + 4) = make_float4(Qr[i*8+4], Qr[i*8+5], Qr[i*8+6], Qr[i*8+7]);
  }
}

// pass 2: sequential combine over chunks; writes chunk-initial state over P
__global__ __launch_bounds__(256) void scan_comb(float* __restrict__ P, const float* __restrict__ Q) {
  const int g = blockIdx.x * 256 + threadIdx.x;  // 0..262143
  const int elem = g & 4095;
  const int bh = g >> 12;
  float s = 0.f;
  for (int c = 0; c < CCH; ++c) {
    const size_t idx = ((size_t)bh * CCH + c) * 4096 + elem;
    const float p = P[idx], qq = Q[idx];
    P[idx] = s;
    s = fmaf(p, s, qq);
  }
}

// pass 3: re-iterate chunk from s_init, emit outputs
__global__ __launch_bounds__(256) void scan_p2(const float* __restrict__ q, const float* __restrict__ k,
    const float* __restrict__ v, const float* __restrict__ al, const float* __restrict__ be,
    const float* __restrict__ Pini, float* __restrict__ o) {
  const int w = threadIdx.x >> 6, lane = threadIdx.x & 63;
  const int g = blockIdx.x * 4 + w;
  const int c = g & 15;
  const int bh = g >> 4;
  const int b = bh >> 4, h = bh & 15;
  const int cb = lane & 7;
  const int r8 = (lane >> 3) * 8, c8 = cb * 8;
  const int t0 = c * LCH;
  const size_t base0 = ((size_t)(b * Sq + t0)) * 1024 + h * 64;
  const size_t ab0   = ((size_t)(b * Sq + t0)) * 16 + h;
  const size_t pbase = ((size_t)bh * CCH + c) * 4096 + (size_t)c8;
  float st[64];
  #pragma unroll
  for (int i = 0; i < 8; ++i) {
    float4 s0 = *(const float4*)(Pini + pbase + (size_t)(r8 + i) * 64);
    float4 s1 = *(const float4*)(Pini + pbase + (size_t)(r8 + i) * 64 + 4);
    st[i*8]   = s0.x; st[i*8+1] = s0.y; st[i*8+2] = s0.z; st[i*8+3] = s0.w;
    st[i*8+4] = s1.x; st[i*8+5] = s1.y; st[i*8+6] = s1.z; st[i*8+7] = s1.w;
  }
  S2 buf[2];
  load_s2(q, k, v, al, be, base0,        ab0,      c8, r8, buf[0]);
  load_s2(q, k, v, al, be, base0 + 1024, ab0 + 16, c8, r8, buf[1]);
  const bool hi4 = (cb & 4), hi2 = (cb & 2), hi1 = (cb & 1);
  for (int tb = 0; tb < LCH; tb += 2) {
    #pragma unroll
    for (int d = 0; d < 2; ++d) {
      const int t = tb + d;
      const S2 s = buf[d];
      const int tn = t + 2;        // dead-load past chunk end: benign
      load_s2(q, k, v, al, be, base0 + (size_t)tn * 1024, ab0 + (size_t)tn * 16, c8, r8, buf[d]);
      const float kcv[8] = {s.kc0.x, s.kc0.y, s.kc0.z, s.kc0.w, s.kc1.x, s.kc1.y, s.kc1.z, s.kc1.w};
      const float qcv[8] = {s.qc0.x, s.qc0.y, s.qc0.z, s.qc0.w, s.qc1.x, s.qc1.y, s.qc1.z, s.qc1.w};
      const float krv[8] = {s.kr0.x, s.kr0.y, s.kr0.z, s.kr0.w, s.kr1.x, s.kr1.y, s.kr1.z, s.kr1.w};
      const float vrv[8] = {s.vr0.x, s.vr0.y, s.vr0.z, s.vr0.w, s.vr1.x, s.vr1.y, s.vr1.z, s.vr1.w};
      const float abt = s.a * s.bt;
      float c1[8], c2[8];
      #pragma unroll
      for (int i = 0; i < 8; ++i) { c1[i] = abt * krv[i]; c2[i] = s.bt * vrv[i]; }
      float p[8];
      #pragma unroll
      for (int i = 0; i < 8; ++i) p[i] = 0.f;
      #pragma unroll
      for (int i = 0; i < 8; ++i)
        #pragma unroll
        for (int j = 0; j < 8; ++j) {
          const int e = i * 8 + j;
          const float A = fmaf(-c1[i], kcv[j], s.a);
          st[e] = fmaf(A, st[e], c2[i] * kcv[j]);
          p[i] = fmaf(st[e], qcv[j], p[i]);
        }
      // reduce-scatter across c_blk: lane (r_blk, cb) ends with row r8+cb total
      float r4[4];
      #pragma unroll
      for (int i = 0; i < 4; ++i) {
        const float send = hi4 ? p[i] : p[i + 4];
        const float recv = __shfl_xor(send, 4);
        r4[i] = (hi4 ? p[i + 4] : p[i]) + recv;
      }
      float r2[2];
      #pragma unroll
      for (int i = 0; i < 2; ++i) {
        const float send = hi2 ? r4[i] : r4[i + 2];
        const float recv = __shfl_xor(send, 2);
        r2[i] = (hi2 ? r4[i + 2] : r4[i]) + recv;
      }
      {
        const float send = hi1 ? r2[0] : r2[1];
        const float recv = __shfl_xor(send, 1);
        const float tot = (hi1 ? r2[1] : r2[0]) + recv;
        o[base0 + (size_t)t * 1024 + lane] = tot;
      }
    }
  }
}

// ---------------- LayerNorm + silu-gate, write bf16 ----------------
__global__ __launch_bounds__(256) void ln_gate_kernel(const float* __restrict__ o, const float* __restrict__ g,
    const float* __restrict__ ln_g, const float* __restrict__ ln_b, u16* __restrict__ y) {
  const int t = blockIdx.x, tid = threadIdx.x;
  const size_t row = (size_t)t * 1024;
  float4 xv = *(const float4*)(o + row + tid * 4);
  float s  = xv.x + xv.y + xv.z + xv.w;
  float s2 = xv.x * xv.x + xv.y * xv.y + xv.z * xv.z + xv.w * xv.w;
  #pragma unroll
  for (int m = 1; m < 64; m <<= 1) { s += __shfl_xor(s, m); s2 += __shfl_xor(s2, m); }
  __shared__ float red[8];
  const int w = tid >> 6, lane = tid & 63;
  if (lane == 0) { red[w] = s; red[4 + w] = s2; }
  __syncthreads();
  s  = red[0] + red[1] + red[2] + red[3];
  s2 = red[4] + red[5] + red[6] + red[7];
  const float mu = s * (1.f / 1024.f);
  const float var = s2 * (1.f / 1024.f) - mu * mu;
  const float rstd = rsqrtf(var + 1e-5f);
  float4 gv = *(const float4*)(g + row + tid * 4);
  float4 lg = *(const float4*)(ln_g + tid * 4);
  float4 lb = *(const float4*)(ln_b + tid * 4);
  ushort4 u;
  u.x = f2bf(((xv.x - mu) * rstd * lg.x + lb.x) * (gv.x * sigmoidf_(gv.x)));
  u.y = f2bf(((xv.y - mu) * rstd * lg.y + lb.y) * (gv.y * sigmoidf_(gv.y)));
  u.z = f2bf(((xv.z - mu) * rstd * lg.z + lb.z) * (gv.z * sigmoidf_(gv.z)));
  u.w = f2bf(((xv.w - mu) * rstd * lg.w + lb.w) * (gv.w * sigmoidf_(gv.w)));
  *(ushort4*)(y + row + tid * 4) = u;
}

extern "C" void kernel_launch(void* const* d_in, const int* in_sizes, int n_in,
                              void* d_out, int out_size, void* d_ws, size_t ws_size,
                              hipStream_t stream) {
  const float* x    = (const float*)d_in[0];
  const float* Wq   = (const float*)d_in[1];
  const float* Wk   = (const float*)d_in[2];
  const float* Wv   = (const float*)d_in[3];
  const float* Wa   = (const float*)d_in[4];
  const float* ba   = (const float*)d_in[5];
  const float* Wb   = (const float*)d_in[6];
  const float* bb   = (const float*)d_in[7];
  const float* Wg   = (const float*)d_in[8];
  const float* Wo   = (const float*)d_in[9];
  const float* ln_g = (const float*)d_in[10];
  const float* ln_b = (const float*)d_in[11];
  float* out = (float*)d_out;
  char* ws = (char*)d_ws;

  u16*   wb  = (u16*)(ws + OFF_WB);
  u16*   xb  = (u16*)(ws + OFF_XB);   // x-bf16 -> Qc -> y-bf16
  float* qf  = (float*)(ws + OFF_Q);
  float* kf  = (float*)(ws + OFF_K);
  float* vf  = (float*)(ws + OFF_V);
  float* gf  = (float*)(ws + OFF_G);
  float* al  = (float*)(ws + OFF_AL);
  float* be  = (float*)(ws + OFF_BE);
  u16*   wab = (u16*)(ws + OFF_P);    // Wab bf16 during GEMM; region later becomes P
  float* Pb  = (float*)(ws + OFF_P);
  float* Qc  = (float*)(ws + OFF_XB); // reuses dead x-bf16 region
  float* of  = (float*)(ws + OFF_O);
  u16*   yb  = xb;

  cvt_x_kernel<<<8192, 256, 0, stream>>>(x, xb);
  cvt_w_kernel<<<dim3(1024, 1, 5), 256, 0, stream>>>(Wq, Wk, Wv, Wg, Wo, wb);
  cvt_ab_kernel<<<128, 256, 0, stream>>>(Wa, Wb, wab);
  // projections q,k,v,g + alpha/beta, with fused l2norm/silu/sigmoid epilogues
  gemm_bt<<<dim3(64, 8, 5), 256, 0, stream>>>(xb, wb, wab, qf, kf, vf, gf, al, be, ba, bb, 1);
  // chunked scan (8x8 tile per lane, 1 wave per (b,h,chunk))
  scan_p1<<<256, 256, 0, stream>>>(kf, vf, al, be, Pb, Qc);
  scan_comb<<<1024, 256, 0, stream>>>(Pb, Qc);
  scan_p2<<<256, 256, 0, stream>>>(qf, kf, vf, al, be, Pb, of);
  // epilogue
  ln_gate_kernel<<<8192, 256, 0, stream>>>(of, gf, ln_g, ln_b, yb);
  gemm_bt<<<dim3(64, 8, 1), 256, 0, stream>>>(yb, wb + (size_t)4 * 1024 * 1024, wab,
                                              out, out, out, out, al, be, ba, bb, 0);
}